// Round 2
// baseline (916.443 us; speedup 1.0000x reference)
//
#include <hip/hip_runtime.h>
#include <math.h>

#define EPSF 1e-8f
#define BM 128
#define BN 128
#define BK 36
#define LDT 132   // padded k-major leading dim: stride%32=4 ok (reads same-k), mult of 4 -> b128 aligned

__device__ __forceinline__ unsigned int ord_from_float(float f) {
  unsigned int u = __float_as_uint(f);
  return (u & 0x80000000u) ? ~u : (u | 0x80000000u);
}

__device__ __forceinline__ float float_from_ord(unsigned int o) {
  return (o & 0x80000000u) ? __uint_as_float(o & 0x7fffffffu)
                           : __uint_as_float(~o);
}

__device__ __forceinline__ unsigned long long shfl_xor_u64(unsigned long long x, int m) {
  int lo = __shfl_xor((int)(unsigned int)(x & 0xffffffffull), m, 64);
  int hi = __shfl_xor((int)(unsigned int)(x >> 32), m, 64);
  return ((unsigned long long)(unsigned int)hi << 32) | (unsigned int)lo;
}

__global__ __launch_bounds__(256) void log_precompute_kernel(
    const float* __restrict__ inp, float* __restrict__ logA, int total4) {
  int idx = blockIdx.x * 256 + threadIdx.x;
  if (idx < total4) {
    float4 v = ((const float4*)inp)[idx];
    float4 r;
    r.x = logf(v.x + EPSF);
    r.y = logf(v.y + EPSF);
    r.z = logf(v.z + EPSF);
    r.w = logf(v.w + EPSF);
    ((float4*)logA)[idx] = r;
  }
}

__global__ __launch_bounds__(64) void rowsum_kernel(const float* __restrict__ inp,
                                                    float* __restrict__ s_in,
                                                    int N, int D) {
  int i = blockIdx.x;
  float s = 0.f;
  for (int d = threadIdx.x; d < D; d += 64) s += inp[(size_t)i * D + d];
  #pragma unroll
  for (int m = 1; m < 64; m <<= 1) s += __shfl_xor(s, m, 64);
  if (threadIdx.x == 0) s_in[i] = s;
}

__global__ __launch_bounds__(64) void stirling_kernel(const float* __restrict__ tgt,
                                                      float* __restrict__ s_st,
                                                      int M, int D) {
  int j = blockIdx.x;
  float s = 0.f;
  for (int d = threadIdx.x; d < D; d += 64) {
    float t = tgt[(size_t)j * D + d];
    if (t > 1.0f)
      s += t * logf(t) - t + 0.5f * logf(6.283185307179586f * t);
  }
  #pragma unroll
  for (int m = 1; m < 64; m <<= 1) s += __shfl_xor(s, m, 64);
  if (threadIdx.x == 0) s_st[j] = s;
}

// cross = log_in @ tgt^T, fused with val = s_st[j] - cross[i,j], per-row min/argmin.
__global__ __launch_bounds__(256) void pair_min_kernel(
    const float* __restrict__ inp, const float* __restrict__ logA,
    const float* __restrict__ tgt, const float* __restrict__ s_st,
    unsigned long long* __restrict__ packed, int N, int M, int D) {
  __shared__ float As[BK][LDT];
  __shared__ float Bs[BK][LDT];
  const int row0 = blockIdx.y * BM;
  const int col0 = blockIdx.x * BN;
  const int t = threadIdx.x;
  const int tx = t & 15;
  const int ty = (t >> 4) & 15;

  float acc[8][8];
  #pragma unroll
  for (int u = 0; u < 8; ++u)
    #pragma unroll
    for (int v = 0; v < 8; ++v) acc[u][v] = 0.f;

  for (int k0 = 0; k0 < D; k0 += BK) {
    const int kc = min(BK, D - k0);
    // stage A and B tiles, k-major layout, i-fastest iteration:
    // consecutive threads write consecutive LDS addresses (conflict-free).
    for (int e = t; e < BM * BK; e += 256) {
      int i = e & (BM - 1);
      int k = e >> 7;            // log2(BM)
      float a = 0.f, b = 0.f;
      if (k < kc) {
        int gk = k0 + k;
        int gi = row0 + i;
        if (gi < N) a = logA ? logA[(size_t)gi * D + gk]
                             : logf(inp[(size_t)gi * D + gk] + EPSF);
        int gj = col0 + i;
        if (gj < M) b = tgt[(size_t)gj * D + gk];
      }
      As[k][i] = a;
      Bs[k][i] = b;
    }
    __syncthreads();
    for (int k = 0; k < kc; ++k) {
      float4 a0 = *(const float4*)(&As[k][ty * 4]);
      float4 a1 = *(const float4*)(&As[k][64 + ty * 4]);
      float4 b0 = *(const float4*)(&Bs[k][tx * 4]);
      float4 b1 = *(const float4*)(&Bs[k][64 + tx * 4]);
      float av[8] = {a0.x, a0.y, a0.z, a0.w, a1.x, a1.y, a1.z, a1.w};
      float bv[8] = {b0.x, b0.y, b0.z, b0.w, b1.x, b1.y, b1.z, b1.w};
      #pragma unroll
      for (int u = 0; u < 8; ++u)
        #pragma unroll
        for (int v = 0; v < 8; ++v)
          acc[u][v] = fmaf(av[u], bv[v], acc[u][v]);
    }
    __syncthreads();
  }

  // fused min/argmin over this block's 128 j-columns
  float stv[8];
  #pragma unroll
  for (int v = 0; v < 8; ++v) {
    int gj = col0 + (v >> 2) * 64 + tx * 4 + (v & 3);
    stv[v] = (gj < M) ? s_st[gj] : 0.f;
  }
  #pragma unroll
  for (int u = 0; u < 8; ++u) {
    unsigned long long bst = ~0ull;
    #pragma unroll
    for (int v = 0; v < 8; ++v) {
      int gj = col0 + (v >> 2) * 64 + tx * 4 + (v & 3);
      if (gj < M) {
        float val = stv[v] - acc[u][v];  // s_in[i] added in finalize (j-independent)
        unsigned long long p =
            ((unsigned long long)ord_from_float(val) << 32) | (unsigned int)gj;
        bst = p < bst ? p : bst;
      }
    }
    // lanes sharing ty (tx=0..15) hold the same rows; reduce across them (one wave)
    #pragma unroll
    for (int m = 1; m < 16; m <<= 1) {
      unsigned long long o = shfl_xor_u64(bst, m);
      bst = o < bst ? o : bst;
    }
    int gi = row0 + (u >> 2) * 64 + ty * 4 + (u & 3);
    if (tx == 0 && gi < N) atomicMin(&packed[gi], bst);
  }
}

__global__ __launch_bounds__(256) void finalize_kernel(
    const unsigned long long* __restrict__ packed,
    const float* __restrict__ s_in, float* __restrict__ out, int N) {
  __shared__ double sh[256];
  double s = 0.0;
  for (int i = threadIdx.x; i < N; i += 256) {
    unsigned long long p = packed[i];
    float val = float_from_ord((unsigned int)(p >> 32));
    out[1 + i] = (float)(unsigned int)(p & 0xffffffffull);
    s += (double)(s_in[i] + val);
  }
  sh[threadIdx.x] = s;
  __syncthreads();
  for (int off = 128; off > 0; off >>= 1) {
    if (threadIdx.x < off) sh[threadIdx.x] += sh[threadIdx.x + off];
    __syncthreads();
  }
  if (threadIdx.x == 0) out[0] = (float)(sh[0] / N);
}

extern "C" void kernel_launch(void* const* d_in, const int* in_sizes, int n_in,
                              void* d_out, int out_size, void* d_ws, size_t ws_size,
                              hipStream_t stream) {
  const float* inp = (const float*)d_in[0];
  const float* tgt = (const float*)d_in[1];
  float* out = (float*)d_out;

  int N = out_size - 1;           // outputs: [loss scalar, match[N]]
  int D = in_sizes[0] / N;
  int M = in_sizes[1] / D;

  float* s_in = (float*)d_ws;
  float* s_st = s_in + N;
  unsigned long long* packed = (unsigned long long*)(s_st + M);
  float* logA = (float*)(packed + N);

  size_t need = (size_t)(N + M) * 4 + (size_t)N * 8 + (size_t)N * D * 4;
  bool use_logA = (ws_size >= need) && (((size_t)N * D) % 4 == 0);

  hipMemsetAsync(packed, 0xFF, (size_t)N * sizeof(unsigned long long), stream);
  rowsum_kernel<<<N, 64, 0, stream>>>(inp, s_in, N, D);
  stirling_kernel<<<M, 64, 0, stream>>>(tgt, s_st, M, D);
  if (use_logA) {
    int total4 = (N * D) / 4;
    log_precompute_kernel<<<(total4 + 255) / 256, 256, 0, stream>>>(inp, logA, total4);
  }

  dim3 grid((M + BN - 1) / BN, (N + BM - 1) / BM);
  pair_min_kernel<<<grid, 256, 0, stream>>>(inp, use_logA ? logA : nullptr, tgt,
                                            s_st, packed, N, M, D);

  finalize_kernel<<<1, 256, 0, stream>>>(packed, s_in, out, N);
}

// Round 3
// 303.534 us; speedup vs baseline: 3.0192x; 3.0192x over previous
//
#include <hip/hip_runtime.h>
#include <math.h>

#define EPSF 1e-8f

typedef _Float16 f16x8 __attribute__((ext_vector_type(8)));
typedef float f32x4 __attribute__((ext_vector_type(4)));

__device__ __forceinline__ unsigned int ord_from_float(float f) {
  unsigned int u = __float_as_uint(f);
  return (u & 0x80000000u) ? ~u : (u | 0x80000000u);
}

__device__ __forceinline__ float float_from_ord(unsigned int o) {
  return (o & 0x80000000u) ? __uint_as_float(o & 0x7fffffffu)
                           : __uint_as_float(~o);
}

__device__ __forceinline__ unsigned long long shfl_xor_u64(unsigned long long x, int m) {
  int lo = __shfl_xor((int)(unsigned int)(x & 0xffffffffull), m, 64);
  int hi = __shfl_xor((int)(unsigned int)(x >> 32), m, 64);
  return ((unsigned long long)(unsigned int)hi << 32) | (unsigned int)lo;
}

// ---------------- small prep kernels ----------------

__global__ __launch_bounds__(64) void rowsum_kernel(const float* __restrict__ inp,
                                                    float* __restrict__ s_in,
                                                    int N, int D) {
  int i = blockIdx.x;
  float s = 0.f;
  for (int d = threadIdx.x; d < D; d += 64) s += inp[(size_t)i * D + d];
  #pragma unroll
  for (int m = 1; m < 64; m <<= 1) s += __shfl_xor(s, m, 64);
  if (threadIdx.x == 0) s_in[i] = s;
}

__global__ __launch_bounds__(64) void stirling_kernel(const float* __restrict__ tgt,
                                                      float* __restrict__ s_st,
                                                      int M, int D) {
  int j = blockIdx.x;
  float s = 0.f;
  for (int d = threadIdx.x; d < D; d += 64) {
    float t = tgt[(size_t)j * D + d];
    if (t > 1.0f)
      s += t * logf(t) - t + 0.5f * logf(6.283185307179586f * t);
  }
  #pragma unroll
  for (int m = 1; m < 64; m <<= 1) s += __shfl_xor(s, m, 64);
  if (threadIdx.x == 0) s_st[j] = s;
}

// split-convert log(inp+eps) (do_log=1) or tgt (do_log=0) into fp16 hi/lo, zero-padded
__global__ __launch_bounds__(64) void split_convert_kernel(
    const float* __restrict__ src, _Float16* __restrict__ hi, _Float16* __restrict__ lo,
    int R, int D, int DP, int do_log) {
  int d = blockIdx.x * 64 + threadIdx.x;
  int r = blockIdx.y;
  if (d >= DP) return;
  float x = 0.f;
  if (r < R && d < D) {
    x = src[(size_t)r * D + d];
    if (do_log) x = logf(x + EPSF);
  }
  _Float16 h = (_Float16)x;
  _Float16 l = (_Float16)(x - (float)h);
  hi[(size_t)r * DP + d] = h;
  lo[(size_t)r * DP + d] = l;
}

// ---------------- MFMA pair-min kernel ----------------
// cross[i][j] = sum_k logA[i][k]*tgt[j][k] via 3-segment fp16 split GEMM,
// fused with val = s_st[j] - cross, per-row min/argmin -> atomicMin(packed).
#define BMM 128
#define BKH 32   // halves per k-step

__global__ __launch_bounds__(256) void mfma_pair_min_kernel(
    const _Float16* __restrict__ Ahi, const _Float16* __restrict__ Alo,
    const _Float16* __restrict__ Bhi, const _Float16* __restrict__ Blo,
    const float* __restrict__ s_st, unsigned long long* __restrict__ packed,
    int N, int M, int DP) {
  __shared__ __align__(16) _Float16 Ash[BMM * BKH];
  __shared__ __align__(16) _Float16 Bsh[BMM * BKH];
  const int t = threadIdx.x;
  const int lane = t & 63;
  const int wid = t >> 6;
  const int wr = wid >> 1, wc = wid & 1;
  const int row0 = blockIdx.y * BMM;
  const int col0 = blockIdx.x * BMM;

  f32x4 acc[4][4] = {};

  const int seg_steps = DP >> 5;  // k-steps per segment
  const int KT = 3 * seg_steps;

  // staging indices: thread stages rows sr0, sr0+64; 16B (8 halves) each
  const int sr0 = t >> 2;   // 0..63
  const int sq = t & 3;     // logical 16B slot within the 64B row

  const int rl = lane & 15;
  const int q = lane >> 4;

  int seg = 0, kl = 0;
  for (int kt = 0; kt < KT; ++kt) {
    const _Float16* __restrict__ Abase = (seg < 2) ? Ahi : Alo;
    const _Float16* __restrict__ Bbase = (seg == 1) ? Blo : Bhi;
    __syncthreads();  // previous iteration's reads complete before overwrite
    #pragma unroll
    for (int h = 0; h < 2; ++h) {
      int r = sr0 + h * 64;
      int s = sq ^ ((r >> 1) & 3);   // XOR swizzle: conflict-free frag reads
      uint4 va = *(const uint4*)(Abase + (size_t)(row0 + r) * DP + kl + sq * 8);
      *(uint4*)(&Ash[r * BKH + s * 8]) = va;
      uint4 vb = *(const uint4*)(Bbase + (size_t)(col0 + r) * DP + kl + sq * 8);
      *(uint4*)(&Bsh[r * BKH + s * 8]) = vb;
    }
    __syncthreads();

    f16x8 af[4], bf[4];
    #pragma unroll
    for (int m = 0; m < 4; ++m) {
      int ra = wr * 64 + m * 16 + rl;
      int sa = q ^ ((ra >> 1) & 3);
      af[m] = *(const f16x8*)(&Ash[ra * BKH + sa * 8]);
      int rb = wc * 64 + m * 16 + rl;
      int sb = q ^ ((rb >> 1) & 3);
      bf[m] = *(const f16x8*)(&Bsh[rb * BKH + sb * 8]);
    }
    #pragma unroll
    for (int m = 0; m < 4; ++m)
      #pragma unroll
      for (int n = 0; n < 4; ++n)
        acc[m][n] = __builtin_amdgcn_mfma_f32_16x16x32_f16(af[m], bf[n], acc[m][n], 0, 0, 0);

    kl += BKH;
    if (kl == DP) { kl = 0; ++seg; }
  }

  // ---- fused min/argmin epilogue ----
  // C/D frag: col = lane&15, row = (lane>>4)*4 + reg   [guide §3, m89-verified]
  float stv[4];
  #pragma unroll
  for (int n = 0; n < 4; ++n) {
    int gj = col0 + wc * 64 + n * 16 + rl;
    stv[n] = (gj < M) ? s_st[gj] : __builtin_inff();
  }
  #pragma unroll
  for (int m = 0; m < 4; ++m) {
    #pragma unroll
    for (int g = 0; g < 4; ++g) {
      int grow = row0 + wr * 64 + m * 16 + q * 4 + g;
      unsigned long long bst = ~0ull;
      #pragma unroll
      for (int n = 0; n < 4; ++n) {
        int gj = col0 + wc * 64 + n * 16 + rl;
        float val = stv[n] - acc[m][n][g];
        unsigned long long p =
            ((unsigned long long)ord_from_float(val) << 32) | (unsigned int)gj;
        if (p < bst) bst = p;
      }
      #pragma unroll
      for (int mm = 1; mm < 16; mm <<= 1) {
        unsigned long long o = shfl_xor_u64(bst, mm);
        if (o < bst) bst = o;
      }
      if (rl == 0 && grow < N) atomicMin(&packed[grow], bst);
    }
  }
}

// ---------------- fp32 fallback (round-2 kernel) ----------------
#define BM 128
#define BN 128
#define BK 36
#define LDT 132

__global__ __launch_bounds__(256) void log_precompute_kernel(
    const float* __restrict__ inp, float* __restrict__ logA, int total4) {
  int idx = blockIdx.x * 256 + threadIdx.x;
  if (idx < total4) {
    float4 v = ((const float4*)inp)[idx];
    float4 r;
    r.x = logf(v.x + EPSF);
    r.y = logf(v.y + EPSF);
    r.z = logf(v.z + EPSF);
    r.w = logf(v.w + EPSF);
    ((float4*)logA)[idx] = r;
  }
}

__global__ __launch_bounds__(256) void pair_min_kernel(
    const float* __restrict__ inp, const float* __restrict__ logA,
    const float* __restrict__ tgt, const float* __restrict__ s_st,
    unsigned long long* __restrict__ packed, int N, int M, int D) {
  __shared__ float As[BK][LDT];
  __shared__ float Bs[BK][LDT];
  const int row0 = blockIdx.y * BM;
  const int col0 = blockIdx.x * BN;
  const int t = threadIdx.x;
  const int tx = t & 15;
  const int ty = (t >> 4) & 15;

  float acc[8][8];
  #pragma unroll
  for (int u = 0; u < 8; ++u)
    #pragma unroll
    for (int v = 0; v < 8; ++v) acc[u][v] = 0.f;

  for (int k0 = 0; k0 < D; k0 += BK) {
    const int kc = min(BK, D - k0);
    for (int e = t; e < BM * BK; e += 256) {
      int i = e & (BM - 1);
      int k = e >> 7;
      float a = 0.f, b = 0.f;
      if (k < kc) {
        int gk = k0 + k;
        int gi = row0 + i;
        if (gi < N) a = logA ? logA[(size_t)gi * D + gk]
                             : logf(inp[(size_t)gi * D + gk] + EPSF);
        int gj = col0 + i;
        if (gj < M) b = tgt[(size_t)gj * D + gk];
      }
      As[k][i] = a;
      Bs[k][i] = b;
    }
    __syncthreads();
    for (int k = 0; k < kc; ++k) {
      float4 a0 = *(const float4*)(&As[k][ty * 4]);
      float4 a1 = *(const float4*)(&As[k][64 + ty * 4]);
      float4 b0 = *(const float4*)(&Bs[k][tx * 4]);
      float4 b1 = *(const float4*)(&Bs[k][64 + tx * 4]);
      float av[8] = {a0.x, a0.y, a0.z, a0.w, a1.x, a1.y, a1.z, a1.w};
      float bv[8] = {b0.x, b0.y, b0.z, b0.w, b1.x, b1.y, b1.z, b1.w};
      #pragma unroll
      for (int u = 0; u < 8; ++u)
        #pragma unroll
        for (int v = 0; v < 8; ++v)
          acc[u][v] = fmaf(av[u], bv[v], acc[u][v]);
    }
    __syncthreads();
  }

  float stv[8];
  #pragma unroll
  for (int v = 0; v < 8; ++v) {
    int gj = col0 + (v >> 2) * 64 + tx * 4 + (v & 3);
    stv[v] = (gj < M) ? s_st[gj] : 0.f;
  }
  #pragma unroll
  for (int u = 0; u < 8; ++u) {
    unsigned long long bst = ~0ull;
    #pragma unroll
    for (int v = 0; v < 8; ++v) {
      int gj = col0 + (v >> 2) * 64 + tx * 4 + (v & 3);
      if (gj < M) {
        float val = stv[v] - acc[u][v];
        unsigned long long p =
            ((unsigned long long)ord_from_float(val) << 32) | (unsigned int)gj;
        bst = p < bst ? p : bst;
      }
    }
    #pragma unroll
    for (int m = 1; m < 16; m <<= 1) {
      unsigned long long o = shfl_xor_u64(bst, m);
      bst = o < bst ? o : bst;
    }
    int gi = row0 + (u >> 2) * 64 + ty * 4 + (u & 3);
    if (tx == 0 && gi < N) atomicMin(&packed[gi], bst);
  }
}

// ---------------- finalize ----------------

__global__ __launch_bounds__(256) void finalize_kernel(
    const unsigned long long* __restrict__ packed,
    const float* __restrict__ s_in, float* __restrict__ out, int N) {
  __shared__ double sh[256];
  double s = 0.0;
  for (int i = threadIdx.x; i < N; i += 256) {
    unsigned long long p = packed[i];
    float val = float_from_ord((unsigned int)(p >> 32));
    out[1 + i] = (float)(unsigned int)(p & 0xffffffffull);
    s += (double)(s_in[i] + val);
  }
  sh[threadIdx.x] = s;
  __syncthreads();
  for (int off = 128; off > 0; off >>= 1) {
    if (threadIdx.x < off) sh[threadIdx.x] += sh[threadIdx.x + off];
    __syncthreads();
  }
  if (threadIdx.x == 0) out[0] = (float)(sh[0] / N);
}

extern "C" void kernel_launch(void* const* d_in, const int* in_sizes, int n_in,
                              void* d_out, int out_size, void* d_ws, size_t ws_size,
                              hipStream_t stream) {
  const float* inp = (const float*)d_in[0];
  const float* tgt = (const float*)d_in[1];
  float* out = (float*)d_out;

  int N = out_size - 1;  // outputs: [loss scalar, match[N]]
  int D = in_sizes[0] / N;
  int M = in_sizes[1] / D;

  int Npad = ((N + BMM - 1) / BMM) * BMM;
  int Mpad = ((M + BMM - 1) / BMM) * BMM;
  int DP = ((D + 31) / 32) * 32;

  char* ws = (char*)d_ws;
  size_t off = 0;
  float* s_in = (float*)(ws + off); off += (size_t)N * 4;
  float* s_st = (float*)(ws + off); off += (size_t)M * 4;
  off = (off + 15) & ~(size_t)15;
  unsigned long long* packed = (unsigned long long*)(ws + off); off += (size_t)N * 8;
  off = (off + 15) & ~(size_t)15;
  _Float16* Ahi = (_Float16*)(ws + off); off += (size_t)Npad * DP * 2;
  _Float16* Alo = (_Float16*)(ws + off); off += (size_t)Npad * DP * 2;
  _Float16* Bhi = (_Float16*)(ws + off); off += (size_t)Mpad * DP * 2;
  _Float16* Blo = (_Float16*)(ws + off); off += (size_t)Mpad * DP * 2;
  size_t need_mfma = off;

  hipMemsetAsync(packed, 0xFF, (size_t)N * sizeof(unsigned long long), stream);
  rowsum_kernel<<<N, 64, 0, stream>>>(inp, s_in, N, D);
  stirling_kernel<<<M, 64, 0, stream>>>(tgt, s_st, M, D);

  if (ws_size >= need_mfma) {
    dim3 cg((DP + 63) / 64, Npad);
    split_convert_kernel<<<cg, 64, 0, stream>>>(inp, Ahi, Alo, N, D, DP, 1);
    dim3 cg2((DP + 63) / 64, Mpad);
    split_convert_kernel<<<cg2, 64, 0, stream>>>(tgt, Bhi, Blo, M, D, DP, 0);
    dim3 grid(Mpad / BMM, Npad / BMM);
    mfma_pair_min_kernel<<<grid, 256, 0, stream>>>(Ahi, Alo, Bhi, Blo, s_st,
                                                   packed, N, M, DP);
  } else {
    // fp32 fallback
    float* logA = (float*)(ws + (((size_t)(N + M) * 4 + (size_t)N * 8 + 15) & ~(size_t)15));
    size_t need_f32 = ((size_t)(N + M) * 4 + (size_t)N * 8 + 15 + (size_t)N * D * 4) ;
    bool use_logA = (ws_size >= need_f32) && (((size_t)N * D) % 4 == 0);
    if (use_logA) {
      int total4 = (N * D) / 4;
      log_precompute_kernel<<<(total4 + 255) / 256, 256, 0, stream>>>(inp, logA, total4);
    }
    dim3 grid((M + BN - 1) / BN, (N + BM - 1) / BM);
    pair_min_kernel<<<grid, 256, 0, stream>>>(inp, use_logA ? logA : nullptr, tgt,
                                              s_st, packed, N, M, D);
  }

  finalize_kernel<<<1, 256, 0, stream>>>(packed, s_in, out, N);
}

// Round 4
// 260.054 us; speedup vs baseline: 3.5241x; 1.1672x over previous
//
#include <hip/hip_runtime.h>
#include <math.h>

#define EPSF 1e-8f

typedef _Float16 f16x8 __attribute__((ext_vector_type(8)));
typedef float f32x4 __attribute__((ext_vector_type(4)));

#define GLOAD_LDS16(g, l)                                                      \
  __builtin_amdgcn_global_load_lds(                                            \
      (const __attribute__((address_space(1))) unsigned int*)(g),              \
      (__attribute__((address_space(3))) unsigned int*)(l), 16, 0, 0)

__device__ __forceinline__ unsigned int ord_from_float(float f) {
  unsigned int u = __float_as_uint(f);
  return (u & 0x80000000u) ? ~u : (u | 0x80000000u);
}

__device__ __forceinline__ float float_from_ord(unsigned int o) {
  return (o & 0x80000000u) ? __uint_as_float(o & 0x7fffffffu)
                           : __uint_as_float(~o);
}

__device__ __forceinline__ unsigned long long shfl_xor_u64(unsigned long long x, int m) {
  int lo = __shfl_xor((int)(unsigned int)(x & 0xffffffffull), m, 64);
  int hi = __shfl_xor((int)(unsigned int)(x >> 32), m, 64);
  return ((unsigned long long)(unsigned int)hi << 32) | (unsigned int)lo;
}

// ---------------- fused prep kernels ----------------
// prep_A: per row, write fp16 hi/lo of log(inp+eps) (zero-padded) AND s_in row sum.
__global__ __launch_bounds__(64) void prep_A_kernel(
    const float* __restrict__ inp, _Float16* __restrict__ hi, _Float16* __restrict__ lo,
    float* __restrict__ s_in, int N, int D, int DP) {
  int r = blockIdx.x;
  float s = 0.f;
  for (int d = threadIdx.x; d < DP; d += 64) {
    float lg = 0.f;
    if (r < N && d < D) {
      float x = inp[(size_t)r * D + d];
      s += x;
      lg = logf(x + EPSF);
    }
    _Float16 h = (_Float16)lg;
    _Float16 l = (_Float16)(lg - (float)h);
    hi[(size_t)r * DP + d] = h;
    lo[(size_t)r * DP + d] = l;
  }
  #pragma unroll
  for (int m = 1; m < 64; m <<= 1) s += __shfl_xor(s, m, 64);
  if (threadIdx.x == 0 && r < N) s_in[r] = s;
}

// prep_B: per row, write fp16 hi/lo of tgt (zero-padded) AND Stirling row sum.
__global__ __launch_bounds__(64) void prep_B_kernel(
    const float* __restrict__ tgt, _Float16* __restrict__ hi, _Float16* __restrict__ lo,
    float* __restrict__ s_st, int M, int D, int DP) {
  int r = blockIdx.x;
  float s = 0.f;
  for (int d = threadIdx.x; d < DP; d += 64) {
    float x = 0.f;
    if (r < M && d < D) {
      x = tgt[(size_t)r * D + d];
      if (x > 1.0f)
        s += x * logf(x) - x + 0.5f * logf(6.283185307179586f * x);
    }
    _Float16 h = (_Float16)x;
    _Float16 l = (_Float16)(x - (float)h);
    hi[(size_t)r * DP + d] = h;
    lo[(size_t)r * DP + d] = l;
  }
  #pragma unroll
  for (int m = 1; m < 64; m <<= 1) s += __shfl_xor(s, m, 64);
  if (threadIdx.x == 0 && r < M) s_st[r] = s;
}

// ---------------- MFMA pair-min kernel ----------------
// cross[i][j] via 3-segment fp16 hi/lo split GEMM (Ahi.Bhi + Ahi.Blo + Alo.Bhi),
// global_load_lds staging with pre-swizzled source, fused min/argmin epilogue.
#define BMM 128

__global__ __launch_bounds__(256) void mfma_pair_min_kernel(
    const _Float16* __restrict__ Ahi, const _Float16* __restrict__ Alo,
    const _Float16* __restrict__ Bhi, const _Float16* __restrict__ Blo,
    const float* __restrict__ s_st, unsigned long long* __restrict__ packed,
    int N, int M, int DP, int gx) {
  __shared__ __align__(16) _Float16 Ash[128 * 32];
  __shared__ __align__(16) _Float16 Bsh[128 * 32];
  const int t = threadIdx.x;
  const int lane = t & 63;
  const int wid = t >> 6;
  const int wr = wid >> 1, wc = wid & 1;

  // bijective XCD-chunk swizzle (m204): same-XCD blocks get adjacent tiles
  const int nwg = gridDim.x;
  const int xcd = blockIdx.x & 7;
  const int idx = blockIdx.x >> 3;
  const int qq = nwg >> 3, rr = nwg & 7;
  const int wg = (xcd < rr ? xcd * (qq + 1) : rr * (qq + 1) + (xcd - rr) * qq) + idx;
  const int row0 = (wg / gx) * BMM;
  const int col0 = (wg % gx) * BMM;

  f32x4 acc[4][4] = {};

  // Staging: wave `wid` owns A/B rows [wid*32, wid*32+32) as 2 wave-loads of
  // 16 rows x 64B each. LDS dest is linear (lane l -> row l>>2, slot l&3); the
  // GLOBAL source slot is pre-swizzled so LDS(row,s) = global(row, s^((row>>1)&3)),
  // matching the swizzled fragment reads below (round-3 verified, 0 conflicts).
  const int srow = lane >> 2;
  const int gs = (lane & 3) ^ ((lane >> 3) & 3);
  const size_t aoff0 = (size_t)(row0 + wid * 32 + srow) * DP + gs * 8;
  const size_t aoff1 = (size_t)(row0 + wid * 32 + 16 + srow) * DP + gs * 8;
  const size_t boff0 = (size_t)(col0 + wid * 32 + srow) * DP + gs * 8;
  const size_t boff1 = (size_t)(col0 + wid * 32 + 16 + srow) * DP + gs * 8;
  _Float16* lA0 = &Ash[wid * 1024];
  _Float16* lA1 = &Ash[wid * 1024 + 512];
  _Float16* lB0 = &Bsh[wid * 1024];
  _Float16* lB1 = &Bsh[wid * 1024 + 512];

  const int rl = lane & 15;
  const int q = lane >> 4;
  const int ksteps = DP >> 5;

  #pragma unroll
  for (int seg = 0; seg < 3; ++seg) {
    const _Float16* Abase = (seg < 2) ? Ahi : Alo;
    const _Float16* Bbase = (seg == 1) ? Blo : Bhi;
    const _Float16* a0 = Abase + aoff0;
    const _Float16* a1 = Abase + aoff1;
    const _Float16* b0 = Bbase + boff0;
    const _Float16* b1 = Bbase + boff1;
    for (int ks = 0; ks < ksteps; ++ks) {
      __syncthreads();  // all waves done reading LDS before overwrite
      GLOAD_LDS16(a0, lA0);
      GLOAD_LDS16(a1, lA1);
      GLOAD_LDS16(b0, lB0);
      GLOAD_LDS16(b1, lB1);
      __syncthreads();  // drains vmcnt -> staged data visible

      f16x8 af[4], bf[4];
      #pragma unroll
      for (int m = 0; m < 4; ++m) {
        int ra = wr * 64 + m * 16 + rl;
        int sa = q ^ ((ra >> 1) & 3);
        af[m] = *(const f16x8*)(&Ash[ra * 32 + sa * 8]);
        int rb = wc * 64 + m * 16 + rl;
        int sb = q ^ ((rb >> 1) & 3);
        bf[m] = *(const f16x8*)(&Bsh[rb * 32 + sb * 8]);
      }
      #pragma unroll
      for (int m = 0; m < 4; ++m)
        #pragma unroll
        for (int n = 0; n < 4; ++n)
          acc[m][n] = __builtin_amdgcn_mfma_f32_16x16x32_f16(af[m], bf[n], acc[m][n], 0, 0, 0);

      a0 += 32; a1 += 32; b0 += 32; b1 += 32;
    }
  }

  // ---- fused min/argmin epilogue ----
  // C/D frag: col = lane&15, row = (lane>>4)*4 + reg   [guide §3, m89-verified]
  float stv[4];
  #pragma unroll
  for (int n = 0; n < 4; ++n) {
    int gj = col0 + wc * 64 + n * 16 + rl;
    stv[n] = (gj < M) ? s_st[gj] : __builtin_inff();
  }
  #pragma unroll
  for (int m = 0; m < 4; ++m) {
    #pragma unroll
    for (int g = 0; g < 4; ++g) {
      int grow = row0 + wr * 64 + m * 16 + q * 4 + g;
      unsigned long long bst = ~0ull;
      #pragma unroll
      for (int n = 0; n < 4; ++n) {
        int gj = col0 + wc * 64 + n * 16 + rl;
        float val = stv[n] - acc[m][n][g];
        unsigned long long p =
            ((unsigned long long)ord_from_float(val) << 32) | (unsigned int)gj;
        if (p < bst) bst = p;
      }
      #pragma unroll
      for (int mm = 1; mm < 16; mm <<= 1) {
        unsigned long long o = shfl_xor_u64(bst, mm);
        if (o < bst) bst = o;
      }
      if (rl == 0 && grow < N) atomicMin(&packed[grow], bst);
    }
  }
}

// ---------------- finalize ----------------

__global__ __launch_bounds__(256) void finalize_kernel(
    const unsigned long long* __restrict__ packed,
    const float* __restrict__ s_in, float* __restrict__ out, int N) {
  __shared__ double sh[256];
  double s = 0.0;
  for (int i = threadIdx.x; i < N; i += 256) {
    unsigned long long p = packed[i];
    float val = float_from_ord((unsigned int)(p >> 32));
    out[1 + i] = (float)(unsigned int)(p & 0xffffffffull);
    s += (double)(s_in[i] + val);
  }
  sh[threadIdx.x] = s;
  __syncthreads();
  for (int off = 128; off > 0; off >>= 1) {
    if (threadIdx.x < off) sh[threadIdx.x] += sh[threadIdx.x + off];
    __syncthreads();
  }
  if (threadIdx.x == 0) out[0] = (float)(sh[0] / N);
}

extern "C" void kernel_launch(void* const* d_in, const int* in_sizes, int n_in,
                              void* d_out, int out_size, void* d_ws, size_t ws_size,
                              hipStream_t stream) {
  const float* inp = (const float*)d_in[0];
  const float* tgt = (const float*)d_in[1];
  float* out = (float*)d_out;

  int N = out_size - 1;  // outputs: [loss scalar, match[N]]
  int D = in_sizes[0] / N;
  int M = in_sizes[1] / D;

  int Npad = ((N + BMM - 1) / BMM) * BMM;
  int Mpad = ((M + BMM - 1) / BMM) * BMM;
  int DP = ((D + 31) / 32) * 32;

  char* ws = (char*)d_ws;
  size_t off = 0;
  float* s_in = (float*)(ws + off); off += (size_t)N * 4;
  float* s_st = (float*)(ws + off); off += (size_t)M * 4;
  off = (off + 15) & ~(size_t)15;
  unsigned long long* packed = (unsigned long long*)(ws + off); off += (size_t)N * 8;
  off = (off + 15) & ~(size_t)15;
  _Float16* Ahi = (_Float16*)(ws + off); off += (size_t)Npad * DP * 2;
  _Float16* Alo = (_Float16*)(ws + off); off += (size_t)Npad * DP * 2;
  _Float16* Bhi = (_Float16*)(ws + off); off += (size_t)Mpad * DP * 2;
  _Float16* Blo = (_Float16*)(ws + off); off += (size_t)Mpad * DP * 2;

  hipMemsetAsync(packed, 0xFF, (size_t)N * sizeof(unsigned long long), stream);

  prep_A_kernel<<<Npad, 64, 0, stream>>>(inp, Ahi, Alo, s_in, N, D, DP);
  prep_B_kernel<<<Mpad, 64, 0, stream>>>(tgt, Bhi, Blo, s_st, M, D, DP);

  int gx = Mpad / BMM, gy = Npad / BMM;
  mfma_pair_min_kernel<<<gx * gy, 256, 0, stream>>>(Ahi, Alo, Bhi, Blo, s_st,
                                                    packed, N, M, DP, gx);

  finalize_kernel<<<1, 256, 0, stream>>>(packed, s_in, out, N);
}